// Round 21
// baseline (98.447 us; speedup 1.0000x reference)
//
#include <hip/hip_runtime.h>
#include <hip/hip_bf16.h>
#include <math.h>

#define NS 16
#define H  48
#define TB 256            // edges per block-tile
#define THREADS 512       // 8 waves; wave-private 32-edge sub-tiles

typedef __attribute__((ext_vector_type(8))) short bf16x8;
typedef __attribute__((ext_vector_type(4))) float f32x4;

// ---- LDS layout (halfword offsets) ----
// W1 frags f=0..2 @ f*768          (half0 512 + half1 256; bias via B1H)
// W2 frags u=0..19 @ 2304 + u*896  (half0 512 + half1 256 + k=48..55 bias 128)
// B1H bf16[48] @ 20224 ; ZO 8 zeros @ 20272
// ATO [256][64] bf16 @ 20280: A -> T -> msg f32[256][32]
//   (col 48 = 1.0 for bias-fold; cols 49..63 = 0)
// XO  [256][16] bf16 @ 36664
#define W2O   2304
#define B1H   20224
#define ZO    20272
#define ATO   20280
#define XO_   36664
#define SMEM_HW 40760    // 81520 B -> best-known config
#define MSGF  10140      // float idx of ATO
#define WCPY  2535       // uint4 count of wpack image (40560 B)

__device__ __forceinline__ short f2bf(float f) {
    unsigned b = __float_as_uint(f);
    unsigned r = (b + 0x7FFFu + ((b >> 16) & 1u)) >> 16;
    return (short)r;
}
__device__ __forceinline__ float bf2f(short s) {
    return __uint_as_float(((unsigned)(unsigned short)s) << 16);
}
// HW packed f32->bf16 (RNE), 2 elements per instruction
__device__ __forceinline__ unsigned cvtpk(float lo, float hi) {
    unsigned r;
    asm("v_cvt_pk_bf16_f32 %0, %1, %2" : "=v"(r) : "v"(lo), "v"(hi));
    return r;
}
__device__ __forceinline__ uint4 pk8(float4 a, float4 b) {
    uint4 q;
    q.x = cvtpk(a.x, a.y); q.y = cvtpk(a.z, a.w);
    q.z = cvtpk(b.x, b.y); q.w = cvtpk(b.z, b.w);
    return q;
}

// ---------- prep (blocks 0-5) + hist (blocks 6+) ----------
__global__ __launch_bounds__(256) void prep_hist_kernel(
    const float* __restrict__ fc1_w, const float* __restrict__ fc2_w,
    const float* __restrict__ fc1_b, const float* __restrict__ fc2_b,
    short* __restrict__ wpack,
    const int* __restrict__ edge_index, int* __restrict__ deg, int E)
{
    if (blockIdx.x < 6) {
        int t = blockIdx.x * 256 + threadIdx.x;
        if (t < 1472) {                 // 23 frags x 64 lanes
            int f = t >> 6, l = t & 63;
            bool isW1 = (f < 3);
            int u = isW1 ? f : (f - 3);
            int n = u * 16 + (l & 15);
            const float* W = isW1 ? fc1_w : fc2_w;
            int ldw = isW1 ? 48 : 320;
            int base = isW1 ? (f * 768) : (W2O + u * 896);
            short* d0 = wpack + base + l * 8;
            #pragma unroll
            for (int i = 0; i < 8; ++i)
                d0[i] = f2bf(W[((l >> 4) * 8 + i) * ldw + n]);
            if (l < 32) {               // half1: k = 32..47
                short* d1 = wpack + base + 512 + l * 8;
                #pragma unroll
                for (int i = 0; i < 8; ++i)
                    d1[i] = f2bf(W[(32 + (l >> 4) * 8 + i) * ldw + n]);
            } else if (!isW1 && l < 48) {   // W2 bias block: k = 48..55
                short* d1 = wpack + base + 512 + l * 8;
                d1[0] = f2bf(fc2_b[n]);
                #pragma unroll
                for (int i = 1; i < 8; ++i) d1[i] = 0;
            }
        } else if (t < 1520) {
            wpack[B1H + (t - 1472)] = f2bf(fc1_b[t - 1472]);
        } else if (t < 1528) {
            wpack[ZO + (t - 1520)] = 0;
        }
    } else {
        int i = (blockIdx.x - 6) * 256 + threadIdx.x;
        if (i < E) atomicAdd(deg + edge_index[i], 1);
    }
}

// ---------- main edge kernel (r20 + s_setprio around MFMA clusters) ----------
__global__ __launch_bounds__(THREADS, 2) void edge_mfma_kernel(
    const float* __restrict__ node_attr,
    const float* __restrict__ edge_attr,
    const float* __restrict__ edge_vec,
    const short* __restrict__ wpack,
    const int*   __restrict__ edge_index,
    unsigned short* __restrict__ msg,   // [E][32] bf16 CSR-ordered messages
    int*   __restrict__ cursor,
    int E)
{
    __shared__ __align__(16) short smemS[SMEM_HW];
    float* smemF = (float*)smemS;
    const int tid = threadIdx.x;
    const int base = blockIdx.x * TB;
    const int l  = tid & 63;
    const int wv = tid >> 6;
    const int g  = l >> 4;
    const int c  = l & 15;
    const int rb = wv * 32;

    const int r = tid >> 1, h = tid & 1;
    const int e = base + r;
    const int ce = e < E ? e : (E - 1);
    const int sI_raw = edge_index[ce];
    const int dI = edge_index[E + ce];

    float shx_r = 0.f, shy_r = 0.f, shz_r = 0.f;
    int slot_r = 0;

    // ---- W image: direct global->LDS DMA (linear dest, lane*16) ----
    for (int idx = tid; idx < WCPY; idx += THREADS) {
        __builtin_amdgcn_global_load_lds(
            (const __attribute__((address_space(1))) void*)(((const uint4*)wpack) + idx),
            (__attribute__((address_space(3))) void*)&smemS[idx * 8],
            16, 0, 0);
    }

    {
        const float* ap = edge_attr + (size_t)ce * H + h * 24;
        float4 A0 = *(const float4*)(ap + 0);
        float4 A1 = *(const float4*)(ap + 4);
        float4 A2 = *(const float4*)(ap + 8);
        float4 A3 = *(const float4*)(ap + 12);
        float4 A4 = *(const float4*)(ap + 16);
        float4 A5 = *(const float4*)(ap + 20);
        const float* xp = node_attr + (size_t)dI * NS + h * 8;
        float4 X0 = *(const float4*)(xp + 0);
        float4 X1 = *(const float4*)(xp + 4);
        if (e >= E) {
            A0 = make_float4(0,0,0,0); A1 = A0; A2 = A0; A3 = A0; A4 = A0; A5 = A0;
            X0 = A0; X1 = A0;
        }
        const int s8 = (r & 7) << 3;
        *(uint4*)&smemS[ATO + r * 64 + (((h*3 + 0) << 3) ^ s8)] = pk8(A0, A1);
        *(uint4*)&smemS[ATO + r * 64 + (((h*3 + 1) << 3) ^ s8)] = pk8(A2, A3);
        *(uint4*)&smemS[ATO + r * 64 + (((h*3 + 2) << 3) ^ s8)] = pk8(A4, A5);
        {
            int az = ATO + r * 64 + (((6 + h) << 3) ^ s8);
            uint4 zq;
            zq.x = (h == 0) ? 0x00003F80u : 0u;
            zq.y = 0u; zq.z = 0u; zq.w = 0u;
            *(uint4*)&smemS[az] = zq;
        }
        *(uint4*)&smemS[XO_ + r * 16 + h * 8] = pk8(X0, X1);
        if (h == 0) {
            int sI = (e < E) ? sI_raw : 0;
            float vx = 0.f, vy = 0.f, vz = 0.f;
            if (e < E) {
                vx = edge_vec[3 * (size_t)ce + 0];
                vy = edge_vec[3 * (size_t)ce + 1];
                vz = edge_vec[3 * (size_t)ce + 2];
            }
            float rn = 1.0f / (sqrtf(vx*vx + vy*vy + vz*vz) + 1e-8f);
            const float c1 = 1.7320508075688772f;
            shx_r = c1 * vx * rn; shy_r = c1 * vy * rn; shz_r = c1 * vz * rn;
            if (e < E) slot_r = atomicAdd(cursor + sI, 1);
        }
    }
    __syncthreads();

    bf16x8 a0[2], a1[2];
    #pragma unroll
    for (int m = 0; m < 2; ++m) {
        int row = rb + m * 16 + c, s8 = (row & 7) << 3;
        a0[m] = *(const bf16x8*)&smemS[ATO + row * 64 + ((g * 8) ^ s8)];
        a1[m] = *(const bf16x8*)&smemS[ATO + row * 64 + ((32 + g * 8) ^ s8)];
    }
    __builtin_amdgcn_s_setprio(1);
    #pragma unroll
    for (int fr = 0; fr < 3; ++fr) {
        bf16x8 b0 = *(const bf16x8*)&smemS[fr * 768 + l * 8];
        bf16x8 b1 = *(const bf16x8*)&smemS[(l < 32) ? (fr * 768 + 512 + l * 8) : ZO];
        float bia = bf2f(smemS[B1H + fr * 16 + c]);
        #pragma unroll
        for (int m = 0; m < 2; ++m) {
            f32x4 acc = {0.f, 0.f, 0.f, 0.f};
            acc = __builtin_amdgcn_mfma_f32_16x16x32_bf16(a0[m], b0, acc, 0, 0, 0);
            acc = __builtin_amdgcn_mfma_f32_16x16x32_bf16(a1[m], b1, acc, 0, 0, 0);
            float t0 = fmaxf(acc[0] + bia, 0.f);
            float t1 = fmaxf(acc[1] + bia, 0.f);
            float t2 = fmaxf(acc[2] + bia, 0.f);
            float t3 = fmaxf(acc[3] + bia, 0.f);
            unsigned p01 = cvtpk(t0, t1);
            unsigned p23 = cvtpk(t2, t3);
            int row0 = rb + m * 16 + g * 4;
            int col = fr * 16 + c;
            smemS[ATO + (row0+0) * 64 + (col ^ (((row0+0) & 7) << 3))] = (short)p01;
            smemS[ATO + (row0+1) * 64 + (col ^ (((row0+1) & 7) << 3))] = (short)(p01 >> 16);
            smemS[ATO + (row0+2) * 64 + (col ^ (((row0+2) & 7) << 3))] = (short)p23;
            smemS[ATO + (row0+3) * 64 + (col ^ (((row0+3) & 7) << 3))] = (short)(p23 >> 16);
        }
    }
    __builtin_amdgcn_s_setprio(0);

    bf16x8 tf0[2], tf1[2];
    #pragma unroll
    for (int m = 0; m < 2; ++m) {
        int row = rb + m * 16 + c, s8 = (row & 7) << 3;
        tf0[m] = *(const bf16x8*)&smemS[ATO + row * 64 + ((g * 8) ^ s8)];
        tf1[m] = *(const bf16x8*)&smemS[ATO + row * 64 + ((32 + g * 8) ^ s8)];
    }
    bf16x8 xr0[2][4], xr1[2][4];
    #pragma unroll
    for (int m = 0; m < 2; ++m)
        #pragma unroll
        for (int j = 0; j < 4; ++j) {
            int row = rb + m * 16 + g * 4 + j;
            xr0[m][j] = *(const bf16x8*)&smemS[XO_ + row * 16];
            xr1[m][j] = *(const bf16x8*)&smemS[XO_ + row * 16 + 8];
        }

    float o0[2][4] = {{0.f,0.f,0.f,0.f},{0.f,0.f,0.f,0.f}};
    float o1[2][4] = {{0.f,0.f,0.f,0.f},{0.f,0.f,0.f,0.f}};
    const int s2 = c >> 2;
    __builtin_amdgcn_s_setprio(1);
    #pragma unroll
    for (int u = 0; u < 20; ++u) {
        const int wb = W2O + u * 896;
        bf16x8 b0 = *(const bf16x8*)&smemS[wb + l * 8];
        bf16x8 b1 = *(const bf16x8*)&smemS[(l < 48) ? (wb + 512 + l * 8) : ZO];
        #pragma unroll
        for (int m = 0; m < 2; ++m) {
            f32x4 acc = {0.f, 0.f, 0.f, 0.f};
            acc = __builtin_amdgcn_mfma_f32_16x16x32_bf16(tf0[m], b0, acc, 0, 0, 0);
            acc = __builtin_amdgcn_mfma_f32_16x16x32_bf16(tf1[m], b1, acc, 0, 0, 0);
            if (u < 16) {
                #pragma unroll
                for (int j = 0; j < 4; ++j) {
                    float xu = bf2f(u < 8 ? xr0[m][j][u] : xr1[m][j][u - 8]);
                    o0[m][j] = fmaf(xu, acc[j], o0[m][j]);
                }
            } else {
                const int f = u - 16;
                #pragma unroll
                for (int j = 0; j < 4; ++j) {
                    float e0, e1, e2, e3;
                    if (f < 2) {
                        e0 = bf2f(xr0[m][j][f*4+0]); e1 = bf2f(xr0[m][j][f*4+1]);
                        e2 = bf2f(xr0[m][j][f*4+2]); e3 = bf2f(xr0[m][j][f*4+3]);
                    } else {
                        e0 = bf2f(xr1[m][j][(f-2)*4+0]); e1 = bf2f(xr1[m][j][(f-2)*4+1]);
                        e2 = bf2f(xr1[m][j][(f-2)*4+2]); e3 = bf2f(xr1[m][j][(f-2)*4+3]);
                    }
                    float xu = e0;
                    xu = (s2 == 1) ? e1 : xu;
                    xu = (s2 == 2) ? e2 : xu;
                    xu = (s2 == 3) ? e3 : xu;
                    o1[m][j] = fmaf(xu, acc[j], o1[m][j]);
                }
            }
        }
    }
    __builtin_amdgcn_s_setprio(0);
    #pragma unroll
    for (int m = 0; m < 2; ++m)
        #pragma unroll
        for (int j = 0; j < 4; ++j) {
            o1[m][j] += __shfl_xor(o1[m][j], 4);
            o1[m][j] += __shfl_xor(o1[m][j], 8);
        }

    const float inv = 0.25f;
    #pragma unroll
    for (int m = 0; m < 2; ++m)
        #pragma unroll
        for (int j = 0; j < 4; ++j) {
            const int rloc = m*16 + g*4 + j;
            const int rr = rb + rloc;
            const int srcl = rloc * 2;
            float shx = __shfl(shx_r, srcl);
            float shy = __shfl(shy_r, srcl);
            float shz = __shfl(shz_r, srcl);
            int lsrc = (g << 4) + (c < 12 ? c / 3 : 0);
            float ov = __shfl(o1[m][j], lsrc);
            int m3 = c - 3 * (c / 3);
            float shm = (m3 == 0) ? shx : ((m3 == 1) ? shy : shz);
            float v2 = (c < 12) ? ov * shm * inv : 0.f;
            smemF[MSGF + rr * 32 + c]      = o0[m][j] * inv;
            smemF[MSGF + rr * 32 + 16 + c] = v2;
        }

    #pragma unroll
    for (int it = 0; it < 4; ++it) {
        int rloc2 = it * 8 + (l >> 3);
        int r2 = rb + rloc2;
        int ch = (l & 7) * 4;
        int e2 = base + r2;
        int slot = __shfl(slot_r, rloc2 * 2);
        float4 val = *(const float4*)&smemF[MSGF + r2 * 32 + ch];
        if (e2 < E) {
            uint2 pv;
            pv.x = cvtpk(val.x, val.y);
            pv.y = cvtpk(val.z, val.w);
            *(uint2*)(msg + (size_t)slot * 32 + ch) = pv;
        }
    }
}

// Unordered CSR offsets: block-local scan + one atomic base per block.
__global__ __launch_bounds__(1024) void offsets_kernel(
    const int* __restrict__ deg, int* __restrict__ starts,
    int* __restrict__ cursor, int* __restrict__ gtotal, int N)
{
    __shared__ int lds[1024];
    __shared__ int base_s;
    const int t = threadIdx.x;
    const int i = blockIdx.x * 1024 + t;
    int v = (i < N) ? deg[i] : 0;
    lds[t] = v;
    __syncthreads();
    int acc = v;
    for (int off = 1; off < 1024; off <<= 1) {
        int u = (t >= off) ? lds[t - off] : 0;
        __syncthreads();
        acc += u;
        lds[t] = acc;
        __syncthreads();
    }
    if (t == 1023) base_s = atomicAdd(gtotal, acc);
    __syncthreads();
    int excl = acc - v;
    if (i < N) {
        int s = base_s + excl;
        starts[i] = s;
        cursor[i] = s;
    }
}

// half-wave per node; u32 loads (2 channels), 2 message-groups, 2-way unroll
__global__ __launch_bounds__(256) void sum_kernel(
    const unsigned short* __restrict__ msg, const int* __restrict__ starts,
    const int* __restrict__ deg, float* __restrict__ out, int N)
{
    int n = (blockIdx.x * blockDim.x + threadIdx.x) >> 5;
    int hl = threadIdx.x & 31;
    if (n >= N) return;
    int s = starts[n], d = deg[n];
    const int kg = hl >> 4;          // message parity group
    const int cp = hl & 15;          // channel pair
    const unsigned short* mb = msg + (size_t)s * 32 + cp * 2;
    float alo0 = 0.f, ahi0 = 0.f, alo1 = 0.f, ahi1 = 0.f;
    int k = kg;
    for (; k + 2 < d; k += 4) {
        unsigned v0 = *(const unsigned*)(mb + (size_t)k * 32);
        unsigned v1 = *(const unsigned*)(mb + (size_t)(k + 2) * 32);
        alo0 += bf2f((short)(v0 & 0xffff)); ahi0 += bf2f((short)(v0 >> 16));
        alo1 += bf2f((short)(v1 & 0xffff)); ahi1 += bf2f((short)(v1 >> 16));
    }
    if (k < d) {
        unsigned v0 = *(const unsigned*)(mb + (size_t)k * 32);
        alo0 += bf2f((short)(v0 & 0xffff)); ahi0 += bf2f((short)(v0 >> 16));
    }
    float alo = alo0 + alo1, ahi = ahi0 + ahi1;
    alo += __shfl_xor(alo, 16);
    ahi += __shfl_xor(ahi, 16);
    if (kg == 0 && cp < 14) {
        float dn = 1.0f / fmaxf((float)d, 1.0f);
        float2 o; o.x = alo * dn; o.y = ahi * dn;
        *(float2*)(out + (size_t)n * 28 + cp * 2) = o;
    }
}

__global__ __launch_bounds__(256) void finalize_kernel(
    float* __restrict__ out, const float* __restrict__ cnt, int total)
{
    int i = blockIdx.x * blockDim.x + threadIdx.x;
    if (i < total) {
        float cv = cnt[i / 28];
        out[i] = out[i] / fmaxf(cv, 1.0f);
    }
}

// compact fp32 fallback (only if workspace is unexpectedly small)
__global__ __launch_bounds__(256) void naive_kernel(
    const float* __restrict__ node_attr, const float* __restrict__ edge_attr,
    const float* __restrict__ edge_vec, const float* __restrict__ fc1_w,
    const float* __restrict__ fc1_b, const float* __restrict__ fc2_w,
    const float* __restrict__ fc2_b, const int* __restrict__ edge_index,
    float* __restrict__ out, float* __restrict__ cnt, int E)
{
    int e = blockIdx.x * blockDim.x + threadIdx.x;
    if (e >= E) return;
    float a[H];
    for (int i = 0; i < H; ++i) a[i] = edge_attr[(size_t)e*H + i];
    int dst = edge_index[E + e];
    float x[NS];
    for (int i = 0; i < NS; ++i) x[i] = node_attr[(size_t)dst*NS + i];
    float o0[NS] = {0}, o1v[4] = {0};
    for (int k = 0; k < H; ++k) {
        float tk = fc1_b[k];
        for (int j = 0; j < H; ++j) tk = fmaf(a[j], fc1_w[j*H + k], tk);
        tk = fmaxf(tk, 0.f);
        const float* row = fc2_w + k*320;
        for (int u = 0; u < NS; ++u) {
            float q = tk * x[u];
            for (int w = 0; w < NS; ++w) o0[w] = fmaf(q, row[u*NS+w], o0[w]);
            for (int v = 0; v < 4; ++v) o1v[v] = fmaf(q, row[256+u*4+v], o1v[v]);
        }
    }
    for (int u = 0; u < NS; ++u) {
        float xu = x[u];
        for (int w = 0; w < NS; ++w) o0[w] = fmaf(xu, fc2_b[u*NS+w], o0[w]);
        for (int v = 0; v < 4; ++v) o1v[v] = fmaf(xu, fc2_b[256+u*4+v], o1v[v]);
    }
    float vx = edge_vec[3*(size_t)e], vy = edge_vec[3*(size_t)e+1], vz = edge_vec[3*(size_t)e+2];
    float rn = 1.0f / (sqrtf(vx*vx+vy*vy+vz*vz) + 1e-8f);
    const float c1 = 1.7320508075688772f;
    float sx = c1*vx*rn, sy = c1*vy*rn, sz = c1*vz*rn;
    int src = edge_index[e];
    float* ob = out + (size_t)src * 28;
    for (int w = 0; w < NS; ++w) atomicAdd(ob + w, o0[w] * 0.25f);
    for (int v = 0; v < 4; ++v) {
        float q = o1v[v] * 0.25f;
        atomicAdd(ob + 16 + 3*v + 0, q * sx);
        atomicAdd(ob + 16 + 3*v + 1, q * sy);
        atomicAdd(ob + 16 + 3*v + 2, q * sz);
    }
    atomicAdd(cnt + src, 1.0f);
}

extern "C" void kernel_launch(void* const* d_in, const int* in_sizes, int n_in,
                              void* d_out, int out_size, void* d_ws, size_t ws_size,
                              hipStream_t stream) {
    const float* node_attr  = (const float*)d_in[0];
    const float* edge_attr  = (const float*)d_in[1];
    const float* edge_vec   = (const float*)d_in[2];
    const float* fc1_w      = (const float*)d_in[3];
    const float* fc1_b      = (const float*)d_in[4];
    const float* fc2_w      = (const float*)d_in[5];
    const float* fc2_b      = (const float*)d_in[6];
    const int*   edge_index = (const int*)d_in[7];

    int E = in_sizes[2] / 3;      // 400000
    int N = in_sizes[0] / NS;     // 50000
    float* out = (float*)d_out;

    size_t msg_b  = (size_t)E * 32 * sizeof(unsigned short);   // bf16 messages
    size_t ints_b = (3 * (size_t)N + 1) * sizeof(int);
    size_t wpk_b  = (size_t)WCPY * 16;   // 40560 B
    size_t need   = msg_b + ints_b + wpk_b;

    if (ws_size >= need) {
        unsigned short* msg = (unsigned short*)d_ws;
        int* ip     = (int*)((char*)d_ws + msg_b);
        int* deg    = ip;                 // [N]
        int* gtotal = ip + N;             // [1]
        int* starts = ip + N + 1;         // [N]
        int* cursor = ip + 2 * N + 1;     // [N]
        short* wpack = (short*)((char*)d_ws + msg_b + ints_b);

        hipMemsetAsync(deg, 0, ((size_t)N + 1) * sizeof(int), stream);
        int nhist = (E + 255) / 256;
        prep_hist_kernel<<<6 + nhist, 256, 0, stream>>>(
            fc1_w, fc2_w, fc1_b, fc2_b, wpack, edge_index, deg, E);
        offsets_kernel<<<(N + 1023) / 1024, 1024, 0, stream>>>(
            deg, starts, cursor, gtotal, N);
        edge_mfma_kernel<<<(E + TB - 1) / TB, THREADS, 0, stream>>>(
            node_attr, edge_attr, edge_vec, wpack, edge_index, msg, cursor, E);
        sum_kernel<<<((size_t)N * 32 + 255) / 256, 256, 0, stream>>>(
            msg, starts, deg, out, N);
    } else {
        float* cnt = (float*)d_ws;
        hipMemsetAsync(d_out, 0, (size_t)out_size * sizeof(float), stream);
        hipMemsetAsync(d_ws, 0, (size_t)N * sizeof(float), stream);
        naive_kernel<<<(E + 255) / 256, 256, 0, stream>>>(
            node_attr, edge_attr, edge_vec, fc1_w, fc1_b, fc2_w, fc2_b,
            edge_index, out, cnt, E);
        int total = N * 28;
        finalize_kernel<<<(total + 255) / 256, 256, 0, stream>>>(out, cnt, total);
    }
}

// Round 22
// 95.813 us; speedup vs baseline: 1.0275x; 1.0275x over previous
//
#include <hip/hip_runtime.h>
#include <hip/hip_bf16.h>
#include <math.h>

#define NS 16
#define H  48
#define TB 256            // edges per block-tile
#define THREADS 512       // 8 waves; wave-private 32-edge sub-tiles

typedef __attribute__((ext_vector_type(8))) short bf16x8;
typedef __attribute__((ext_vector_type(4))) float f32x4;

// ---- LDS layout (halfword offsets) ----
// W1 frags f=0..2 @ f*768          (half0 512 + half1 256; bias via B1H)
// W2 frags u=0..19 @ 2304 + u*896  (half0 512 + half1 256 + k=48..55 bias 128)
// B1H bf16[48] @ 20224 ; ZO 8 zeros @ 20272
// ATO [256][64] bf16 @ 20280: A -> T -> msg f32[256][32]
//   (col 48 = 1.0 for bias-fold; cols 49..63 = 0)
// XO  [256][16] bf16 @ 36664
#define W2O   2304
#define B1H   20224
#define ZO    20272
#define ATO   20280
#define XO_   36664
#define SMEM_HW 40760    // 81520 B -> best-known config (r13/r14/r17/r19/r20)
#define MSGF  10140      // float idx of ATO
#define WCPY  2535       // uint4 count of wpack image (40560 B)

__device__ __forceinline__ short f2bf(float f) {
    unsigned b = __float_as_uint(f);
    unsigned r = (b + 0x7FFFu + ((b >> 16) & 1u)) >> 16;
    return (short)r;
}
__device__ __forceinline__ float bf2f(short s) {
    return __uint_as_float(((unsigned)(unsigned short)s) << 16);
}
// HW packed f32->bf16 (RNE), 2 elements per instruction
__device__ __forceinline__ unsigned cvtpk(float lo, float hi) {
    unsigned r;
    asm("v_cvt_pk_bf16_f32 %0, %1, %2" : "=v"(r) : "v"(lo), "v"(hi));
    return r;
}
__device__ __forceinline__ uint4 pk8(float4 a, float4 b) {
    uint4 q;
    q.x = cvtpk(a.x, a.y); q.y = cvtpk(a.z, a.w);
    q.z = cvtpk(b.x, b.y); q.w = cvtpk(b.z, b.w);
    return q;
}

// ---------- prep (blocks 0-5) + hist (blocks 6+) ----------
__global__ __launch_bounds__(256) void prep_hist_kernel(
    const float* __restrict__ fc1_w, const float* __restrict__ fc2_w,
    const float* __restrict__ fc1_b, const float* __restrict__ fc2_b,
    short* __restrict__ wpack,
    const int* __restrict__ edge_index, int* __restrict__ deg, int E)
{
    if (blockIdx.x < 6) {
        int t = blockIdx.x * 256 + threadIdx.x;
        if (t < 1472) {                 // 23 frags x 64 lanes
            int f = t >> 6, l = t & 63;
            bool isW1 = (f < 3);
            int u = isW1 ? f : (f - 3);
            int n = u * 16 + (l & 15);
            const float* W = isW1 ? fc1_w : fc2_w;
            int ldw = isW1 ? 48 : 320;
            int base = isW1 ? (f * 768) : (W2O + u * 896);
            short* d0 = wpack + base + l * 8;
            #pragma unroll
            for (int i = 0; i < 8; ++i)
                d0[i] = f2bf(W[((l >> 4) * 8 + i) * ldw + n]);
            if (l < 32) {               // half1: k = 32..47
                short* d1 = wpack + base + 512 + l * 8;
                #pragma unroll
                for (int i = 0; i < 8; ++i)
                    d1[i] = f2bf(W[(32 + (l >> 4) * 8 + i) * ldw + n]);
            } else if (!isW1 && l < 48) {   // W2 bias block: k = 48..55
                short* d1 = wpack + base + 512 + l * 8;
                d1[0] = f2bf(fc2_b[n]);
                #pragma unroll
                for (int i = 1; i < 8; ++i) d1[i] = 0;
            }
        } else if (t < 1520) {
            wpack[B1H + (t - 1472)] = f2bf(fc1_b[t - 1472]);
        } else if (t < 1528) {
            wpack[ZO + (t - 1520)] = 0;
        }
    } else {
        int i = (blockIdx.x - 6) * 256 + threadIdx.x;
        if (i < E) atomicAdd(deg + edge_index[i], 1);
    }
}

// ---------- main edge kernel (best-known: r19 + global_load_lds W-copy) ----------
__global__ __launch_bounds__(THREADS, 2) void edge_mfma_kernel(
    const float* __restrict__ node_attr,
    const float* __restrict__ edge_attr,
    const float* __restrict__ edge_vec,
    const short* __restrict__ wpack,
    const int*   __restrict__ edge_index,
    unsigned short* __restrict__ msg,   // [E][32] bf16 CSR-ordered messages
    int*   __restrict__ cursor,
    int E)
{
    __shared__ __align__(16) short smemS[SMEM_HW];
    float* smemF = (float*)smemS;
    const int tid = threadIdx.x;
    const int base = blockIdx.x * TB;
    const int l  = tid & 63;
    const int wv = tid >> 6;
    const int g  = l >> 4;
    const int c  = l & 15;
    const int rb = wv * 32;

    const int r = tid >> 1, h = tid & 1;
    const int e = base + r;
    const int ce = e < E ? e : (E - 1);
    const int sI_raw = edge_index[ce];
    const int dI = edge_index[E + ce];

    float shx_r = 0.f, shy_r = 0.f, shz_r = 0.f;
    int slot_r = 0;

    // ---- W image: direct global->LDS DMA (wave-uniform base + lane*16,
    //      linear dest -> satisfies the global_load_lds layout constraint).
    //      No VGPR round-trip; the __syncthreads vmcnt(0) drain covers it.
    for (int idx = tid; idx < WCPY; idx += THREADS) {
        __builtin_amdgcn_global_load_lds(
            (const __attribute__((address_space(1))) void*)(((const uint4*)wpack) + idx),
            (__attribute__((address_space(3))) void*)&smemS[idx * 8],
            16, 0, 0);
    }

    {
        const float* ap = edge_attr + (size_t)ce * H + h * 24;
        float4 A0 = *(const float4*)(ap + 0);
        float4 A1 = *(const float4*)(ap + 4);
        float4 A2 = *(const float4*)(ap + 8);
        float4 A3 = *(const float4*)(ap + 12);
        float4 A4 = *(const float4*)(ap + 16);
        float4 A5 = *(const float4*)(ap + 20);
        const float* xp = node_attr + (size_t)dI * NS + h * 8;
        float4 X0 = *(const float4*)(xp + 0);
        float4 X1 = *(const float4*)(xp + 4);
        if (e >= E) {
            A0 = make_float4(0,0,0,0); A1 = A0; A2 = A0; A3 = A0; A4 = A0; A5 = A0;
            X0 = A0; X1 = A0;
        }
        const int s8 = (r & 7) << 3;
        *(uint4*)&smemS[ATO + r * 64 + (((h*3 + 0) << 3) ^ s8)] = pk8(A0, A1);
        *(uint4*)&smemS[ATO + r * 64 + (((h*3 + 1) << 3) ^ s8)] = pk8(A2, A3);
        *(uint4*)&smemS[ATO + r * 64 + (((h*3 + 2) << 3) ^ s8)] = pk8(A4, A5);
        {
            int az = ATO + r * 64 + (((6 + h) << 3) ^ s8);
            uint4 zq;
            zq.x = (h == 0) ? 0x00003F80u : 0u;
            zq.y = 0u; zq.z = 0u; zq.w = 0u;
            *(uint4*)&smemS[az] = zq;
        }
        *(uint4*)&smemS[XO_ + r * 16 + h * 8] = pk8(X0, X1);
        if (h == 0) {
            int sI = (e < E) ? sI_raw : 0;
            float vx = 0.f, vy = 0.f, vz = 0.f;
            if (e < E) {
                vx = edge_vec[3 * (size_t)ce + 0];
                vy = edge_vec[3 * (size_t)ce + 1];
                vz = edge_vec[3 * (size_t)ce + 2];
            }
            float rn = 1.0f / (sqrtf(vx*vx + vy*vy + vz*vz) + 1e-8f);
            const float c1 = 1.7320508075688772f;
            shx_r = c1 * vx * rn; shy_r = c1 * vy * rn; shz_r = c1 * vz * rn;
            if (e < E) slot_r = atomicAdd(cursor + sI, 1);
        }
    }
    __syncthreads();

    bf16x8 a0[2], a1[2];
    #pragma unroll
    for (int m = 0; m < 2; ++m) {
        int row = rb + m * 16 + c, s8 = (row & 7) << 3;
        a0[m] = *(const bf16x8*)&smemS[ATO + row * 64 + ((g * 8) ^ s8)];
        a1[m] = *(const bf16x8*)&smemS[ATO + row * 64 + ((32 + g * 8) ^ s8)];
    }
    #pragma unroll
    for (int fr = 0; fr < 3; ++fr) {
        bf16x8 b0 = *(const bf16x8*)&smemS[fr * 768 + l * 8];
        bf16x8 b1 = *(const bf16x8*)&smemS[(l < 32) ? (fr * 768 + 512 + l * 8) : ZO];
        float bia = bf2f(smemS[B1H + fr * 16 + c]);
        #pragma unroll
        for (int m = 0; m < 2; ++m) {
            f32x4 acc = {0.f, 0.f, 0.f, 0.f};
            acc = __builtin_amdgcn_mfma_f32_16x16x32_bf16(a0[m], b0, acc, 0, 0, 0);
            acc = __builtin_amdgcn_mfma_f32_16x16x32_bf16(a1[m], b1, acc, 0, 0, 0);
            float t0 = fmaxf(acc[0] + bia, 0.f);
            float t1 = fmaxf(acc[1] + bia, 0.f);
            float t2 = fmaxf(acc[2] + bia, 0.f);
            float t3 = fmaxf(acc[3] + bia, 0.f);
            unsigned p01 = cvtpk(t0, t1);
            unsigned p23 = cvtpk(t2, t3);
            int row0 = rb + m * 16 + g * 4;
            int col = fr * 16 + c;
            smemS[ATO + (row0+0) * 64 + (col ^ (((row0+0) & 7) << 3))] = (short)p01;
            smemS[ATO + (row0+1) * 64 + (col ^ (((row0+1) & 7) << 3))] = (short)(p01 >> 16);
            smemS[ATO + (row0+2) * 64 + (col ^ (((row0+2) & 7) << 3))] = (short)p23;
            smemS[ATO + (row0+3) * 64 + (col ^ (((row0+3) & 7) << 3))] = (short)(p23 >> 16);
        }
    }

    bf16x8 tf0[2], tf1[2];
    #pragma unroll
    for (int m = 0; m < 2; ++m) {
        int row = rb + m * 16 + c, s8 = (row & 7) << 3;
        tf0[m] = *(const bf16x8*)&smemS[ATO + row * 64 + ((g * 8) ^ s8)];
        tf1[m] = *(const bf16x8*)&smemS[ATO + row * 64 + ((32 + g * 8) ^ s8)];
    }
    bf16x8 xr0[2][4], xr1[2][4];
    #pragma unroll
    for (int m = 0; m < 2; ++m)
        #pragma unroll
        for (int j = 0; j < 4; ++j) {
            int row = rb + m * 16 + g * 4 + j;
            xr0[m][j] = *(const bf16x8*)&smemS[XO_ + row * 16];
            xr1[m][j] = *(const bf16x8*)&smemS[XO_ + row * 16 + 8];
        }

    float o0[2][4] = {{0.f,0.f,0.f,0.f},{0.f,0.f,0.f,0.f}};
    float o1[2][4] = {{0.f,0.f,0.f,0.f},{0.f,0.f,0.f,0.f}};
    const int s2 = c >> 2;
    #pragma unroll
    for (int u = 0; u < 20; ++u) {
        const int wb = W2O + u * 896;
        bf16x8 b0 = *(const bf16x8*)&smemS[wb + l * 8];
        bf16x8 b1 = *(const bf16x8*)&smemS[(l < 48) ? (wb + 512 + l * 8) : ZO];
        #pragma unroll
        for (int m = 0; m < 2; ++m) {
            f32x4 acc = {0.f, 0.f, 0.f, 0.f};
            acc = __builtin_amdgcn_mfma_f32_16x16x32_bf16(tf0[m], b0, acc, 0, 0, 0);
            acc = __builtin_amdgcn_mfma_f32_16x16x32_bf16(tf1[m], b1, acc, 0, 0, 0);
            if (u < 16) {
                #pragma unroll
                for (int j = 0; j < 4; ++j) {
                    float xu = bf2f(u < 8 ? xr0[m][j][u] : xr1[m][j][u - 8]);
                    o0[m][j] = fmaf(xu, acc[j], o0[m][j]);
                }
            } else {
                const int f = u - 16;
                #pragma unroll
                for (int j = 0; j < 4; ++j) {
                    float e0, e1, e2, e3;
                    if (f < 2) {
                        e0 = bf2f(xr0[m][j][f*4+0]); e1 = bf2f(xr0[m][j][f*4+1]);
                        e2 = bf2f(xr0[m][j][f*4+2]); e3 = bf2f(xr0[m][j][f*4+3]);
                    } else {
                        e0 = bf2f(xr1[m][j][(f-2)*4+0]); e1 = bf2f(xr1[m][j][(f-2)*4+1]);
                        e2 = bf2f(xr1[m][j][(f-2)*4+2]); e3 = bf2f(xr1[m][j][(f-2)*4+3]);
                    }
                    float xu = e0;
                    xu = (s2 == 1) ? e1 : xu;
                    xu = (s2 == 2) ? e2 : xu;
                    xu = (s2 == 3) ? e3 : xu;
                    o1[m][j] = fmaf(xu, acc[j], o1[m][j]);
                }
            }
        }
    }
    #pragma unroll
    for (int m = 0; m < 2; ++m)
        #pragma unroll
        for (int j = 0; j < 4; ++j) {
            o1[m][j] += __shfl_xor(o1[m][j], 4);
            o1[m][j] += __shfl_xor(o1[m][j], 8);
        }

    const float inv = 0.25f;
    #pragma unroll
    for (int m = 0; m < 2; ++m)
        #pragma unroll
        for (int j = 0; j < 4; ++j) {
            const int rloc = m*16 + g*4 + j;
            const int rr = rb + rloc;
            const int srcl = rloc * 2;
            float shx = __shfl(shx_r, srcl);
            float shy = __shfl(shy_r, srcl);
            float shz = __shfl(shz_r, srcl);
            int lsrc = (g << 4) + (c < 12 ? c / 3 : 0);
            float ov = __shfl(o1[m][j], lsrc);
            int m3 = c - 3 * (c / 3);
            float shm = (m3 == 0) ? shx : ((m3 == 1) ? shy : shz);
            float v2 = (c < 12) ? ov * shm * inv : 0.f;
            smemF[MSGF + rr * 32 + c]      = o0[m][j] * inv;
            smemF[MSGF + rr * 32 + 16 + c] = v2;
        }

    #pragma unroll
    for (int it = 0; it < 4; ++it) {
        int rloc2 = it * 8 + (l >> 3);
        int r2 = rb + rloc2;
        int ch = (l & 7) * 4;
        int e2 = base + r2;
        int slot = __shfl(slot_r, rloc2 * 2);
        float4 val = *(const float4*)&smemF[MSGF + r2 * 32 + ch];
        if (e2 < E) {
            uint2 pv;
            pv.x = cvtpk(val.x, val.y);
            pv.y = cvtpk(val.z, val.w);
            *(uint2*)(msg + (size_t)slot * 32 + ch) = pv;
        }
    }
}

// Unordered CSR offsets: block-local scan + one atomic base per block.
__global__ __launch_bounds__(1024) void offsets_kernel(
    const int* __restrict__ deg, int* __restrict__ starts,
    int* __restrict__ cursor, int* __restrict__ gtotal, int N)
{
    __shared__ int lds[1024];
    __shared__ int base_s;
    const int t = threadIdx.x;
    const int i = blockIdx.x * 1024 + t;
    int v = (i < N) ? deg[i] : 0;
    lds[t] = v;
    __syncthreads();
    int acc = v;
    for (int off = 1; off < 1024; off <<= 1) {
        int u = (t >= off) ? lds[t - off] : 0;
        __syncthreads();
        acc += u;
        lds[t] = acc;
        __syncthreads();
    }
    if (t == 1023) base_s = atomicAdd(gtotal, acc);
    __syncthreads();
    int excl = acc - v;
    if (i < N) {
        int s = base_s + excl;
        starts[i] = s;
        cursor[i] = s;
    }
}

// half-wave per node; u32 loads (2 channels), 2 message-groups, 2-way unroll
__global__ __launch_bounds__(256) void sum_kernel(
    const unsigned short* __restrict__ msg, const int* __restrict__ starts,
    const int* __restrict__ deg, float* __restrict__ out, int N)
{
    int n = (blockIdx.x * blockDim.x + threadIdx.x) >> 5;
    int hl = threadIdx.x & 31;
    if (n >= N) return;
    int s = starts[n], d = deg[n];
    const int kg = hl >> 4;          // message parity group
    const int cp = hl & 15;          // channel pair
    const unsigned short* mb = msg + (size_t)s * 32 + cp * 2;
    float alo0 = 0.f, ahi0 = 0.f, alo1 = 0.f, ahi1 = 0.f;
    int k = kg;
    for (; k + 2 < d; k += 4) {
        unsigned v0 = *(const unsigned*)(mb + (size_t)k * 32);
        unsigned v1 = *(const unsigned*)(mb + (size_t)(k + 2) * 32);
        alo0 += bf2f((short)(v0 & 0xffff)); ahi0 += bf2f((short)(v0 >> 16));
        alo1 += bf2f((short)(v1 & 0xffff)); ahi1 += bf2f((short)(v1 >> 16));
    }
    if (k < d) {
        unsigned v0 = *(const unsigned*)(mb + (size_t)k * 32);
        alo0 += bf2f((short)(v0 & 0xffff)); ahi0 += bf2f((short)(v0 >> 16));
    }
    float alo = alo0 + alo1, ahi = ahi0 + ahi1;
    alo += __shfl_xor(alo, 16);
    ahi += __shfl_xor(ahi, 16);
    if (kg == 0 && cp < 14) {
        float dn = 1.0f / fmaxf((float)d, 1.0f);
        float2 o; o.x = alo * dn; o.y = ahi * dn;
        *(float2*)(out + (size_t)n * 28 + cp * 2) = o;
    }
}

__global__ __launch_bounds__(256) void finalize_kernel(
    float* __restrict__ out, const float* __restrict__ cnt, int total)
{
    int i = blockIdx.x * blockDim.x + threadIdx.x;
    if (i < total) {
        float cv = cnt[i / 28];
        out[i] = out[i] / fmaxf(cv, 1.0f);
    }
}

// compact fp32 fallback (only if workspace is unexpectedly small)
__global__ __launch_bounds__(256) void naive_kernel(
    const float* __restrict__ node_attr, const float* __restrict__ edge_attr,
    const float* __restrict__ edge_vec, const float* __restrict__ fc1_w,
    const float* __restrict__ fc1_b, const float* __restrict__ fc2_w,
    const float* __restrict__ fc2_b, const int* __restrict__ edge_index,
    float* __restrict__ out, float* __restrict__ cnt, int E)
{
    int e = blockIdx.x * blockDim.x + threadIdx.x;
    if (e >= E) return;
    float a[H];
    for (int i = 0; i < H; ++i) a[i] = edge_attr[(size_t)e*H + i];
    int dst = edge_index[E + e];
    float x[NS];
    for (int i = 0; i < NS; ++i) x[i] = node_attr[(size_t)dst*NS + i];
    float o0[NS] = {0}, o1v[4] = {0};
    for (int k = 0; k < H; ++k) {
        float tk = fc1_b[k];
        for (int j = 0; j < H; ++j) tk = fmaf(a[j], fc1_w[j*H + k], tk);
        tk = fmaxf(tk, 0.f);
        const float* row = fc2_w + k*320;
        for (int u = 0; u < NS; ++u) {
            float q = tk * x[u];
            for (int w = 0; w < NS; ++w) o0[w] = fmaf(q, row[u*NS+w], o0[w]);
            for (int v = 0; v < 4; ++v) o1v[v] = fmaf(q, row[256+u*4+v], o1v[v]);
        }
    }
    for (int u = 0; u < NS; ++u) {
        float xu = x[u];
        for (int w = 0; w < NS; ++w) o0[w] = fmaf(xu, fc2_b[u*NS+w], o0[w]);
        for (int v = 0; v < 4; ++v) o1v[v] = fmaf(xu, fc2_b[256+u*4+v], o1v[v]);
    }
    float vx = edge_vec[3*(size_t)e], vy = edge_vec[3*(size_t)e+1], vz = edge_vec[3*(size_t)e+2];
    float rn = 1.0f / (sqrtf(vx*vx+vy*vy+vz*vz) + 1e-8f);
    const float c1 = 1.7320508075688772f;
    float sx = c1*vx*rn, sy = c1*vy*rn, sz = c1*vz*rn;
    int src = edge_index[e];
    float* ob = out + (size_t)src * 28;
    for (int w = 0; w < NS; ++w) atomicAdd(ob + w, o0[w] * 0.25f);
    for (int v = 0; v < 4; ++v) {
        float q = o1v[v] * 0.25f;
        atomicAdd(ob + 16 + 3*v + 0, q * sx);
        atomicAdd(ob + 16 + 3*v + 1, q * sy);
        atomicAdd(ob + 16 + 3*v + 2, q * sz);
    }
    atomicAdd(cnt + src, 1.0f);
}

extern "C" void kernel_launch(void* const* d_in, const int* in_sizes, int n_in,
                              void* d_out, int out_size, void* d_ws, size_t ws_size,
                              hipStream_t stream) {
    const float* node_attr  = (const float*)d_in[0];
    const float* edge_attr  = (const float*)d_in[1];
    const float* edge_vec   = (const float*)d_in[2];
    const float* fc1_w      = (const float*)d_in[3];
    const float* fc1_b      = (const float*)d_in[4];
    const float* fc2_w      = (const float*)d_in[5];
    const float* fc2_b      = (const float*)d_in[6];
    const int*   edge_index = (const int*)d_in[7];

    int E = in_sizes[2] / 3;      // 400000
    int N = in_sizes[0] / NS;     // 50000
    float* out = (float*)d_out;

    size_t msg_b  = (size_t)E * 32 * sizeof(unsigned short);   // bf16 messages
    size_t ints_b = (3 * (size_t)N + 1) * sizeof(int);
    size_t wpk_b  = (size_t)WCPY * 16;   // 40560 B
    size_t need   = msg_b + ints_b + wpk_b;

    if (ws_size >= need) {
        unsigned short* msg = (unsigned short*)d_ws;
        int* ip     = (int*)((char*)d_ws + msg_b);
        int* deg    = ip;                 // [N]
        int* gtotal = ip + N;             // [1]
        int* starts = ip + N + 1;         // [N]
        int* cursor = ip + 2 * N + 1;     // [N]
        short* wpack = (short*)((char*)d_ws + msg_b + ints_b);

        hipMemsetAsync(deg, 0, ((size_t)N + 1) * sizeof(int), stream);
        int nhist = (E + 255) / 256;
        prep_hist_kernel<<<6 + nhist, 256, 0, stream>>>(
            fc1_w, fc2_w, fc1_b, fc2_b, wpack, edge_index, deg, E);
        offsets_kernel<<<(N + 1023) / 1024, 1024, 0, stream>>>(
            deg, starts, cursor, gtotal, N);
        edge_mfma_kernel<<<(E + TB - 1) / TB, THREADS, 0, stream>>>(
            node_attr, edge_attr, edge_vec, wpack, edge_index, msg, cursor, E);
        sum_kernel<<<((size_t)N * 32 + 255) / 256, 256, 0, stream>>>(
            msg, starts, deg, out, N);
    } else {
        float* cnt = (float*)d_ws;
        hipMemsetAsync(d_out, 0, (size_t)out_size * sizeof(float), stream);
        hipMemsetAsync(d_ws, 0, (size_t)N * sizeof(float), stream);
        naive_kernel<<<(E + 255) / 256, 256, 0, stream>>>(
            node_attr, edge_attr, edge_vec, fc1_w, fc1_b, fc2_w, fc2_b,
            edge_index, out, cnt, E);
        int total = N * 28;
        finalize_kernel<<<(total + 255) / 256, 256, 0, stream>>>(out, cnt, total);
    }
}